// Round 7
// baseline (277.879 us; speedup 1.0000x reference)
//
#include <hip/hip_runtime.h>

// SelfAttention: GN -> 1x1 QKV -> softmax attention (HW=1024) -> 1x1 proj + residual
// B=16, C=512, HW=1024, GROUPS=32, EPS=1e-5, scale=C^-0.5
//
// Round 7: (a) XCD-aware block remap per GEMM: pin blocks sharing an A-tile / batch /
// B-tile to one XCD so the shared working set (2-3.5 MB) stays in that XCD's 4 MB L2
// (R6 measured 4x HBM over-fetch from round-robin XCD scatter). (b) softmax fused into
// PV (MODE 3): block prologue computes exact row max/sumexp for its 128 S-rows, K-loop
// applies exp2(s*log2e - c_row) to A-frags in registers, epilogue scales by 1/l.
// GEMM core = R4 (best measured): barriered double-buffer, global_load_lds w16, XOR
// chunk swizzle, 128x128 tiles, acc[4][4]. Layouts (all [free][K]):
//   xnT [b][hw][c], qkT [b][hw][q|k], v [b][c][hw], S raw [b][i][j], aoutT [b][hw][c]

typedef _Float16 f16;
typedef _Float16 f16x8 __attribute__((ext_vector_type(8)));
typedef _Float16 f16x4 __attribute__((ext_vector_type(4)));
typedef float fx4 __attribute__((ext_vector_type(4)));

#define LOG2E 1.44269504088896f

__device__ __forceinline__ void gload16(const f16* g, f16* l) {
    __builtin_amdgcn_global_load_lds((const __attribute__((address_space(1))) void*)g,
                                     (__attribute__((address_space(3))) void*)l, 16, 0, 0);
}

// ---------------- weight convert: fp32 -> f16, n4 float4 chunks ----------------
__global__ __launch_bounds__(256)
void wconv_kernel(const float* __restrict__ w, f16* __restrict__ o, int n4)
{
    int i = blockIdx.x * 256 + threadIdx.x;
    if (i < n4) {
        float4 v = *(const float4*)(w + i * 4);
        f16x4 h;
        h[0] = (f16)v.x; h[1] = (f16)v.y; h[2] = (f16)v.z; h[3] = (f16)v.w;
        *(f16x4*)(o + i * 4) = h;
    }
}

// ---------------- GroupNorm: x fp32 [16][512][1024] -> xnT f16 [16][1024][512] ----------------
__global__ __launch_bounds__(256)
void groupnorm_kernel(const float* __restrict__ x, const float* __restrict__ gamma,
                      const float* __restrict__ beta, f16* __restrict__ xnT)
{
    __shared__ float red[256], red2[256];
    __shared__ float mu_s, rs_s;
    __shared__ __align__(16) f16 T[16][1040];  // [ch][hw], padded
    const int blk = blockIdx.x;                // b*32 + g
    const int b = blk >> 5, g = blk & 31;
    const long base = (long)blk * 16384;       // 16 ch * 1024 hw
    const int tid = threadIdx.x;
    const float4* xv = (const float4*)(x + base);

    float4 xr[16];
    float s = 0.f, s2 = 0.f;
#pragma unroll
    for (int i = 0; i < 16; i++) {
        float4 v = xv[tid + i * 256];
        xr[i] = v;
        s  += v.x + v.y + v.z + v.w;
        s2 += v.x * v.x + v.y * v.y + v.z * v.z + v.w * v.w;
    }
    red[tid] = s; red2[tid] = s2;
    __syncthreads();
    for (int off = 128; off > 0; off >>= 1) {
        if (tid < off) { red[tid] += red[tid + off]; red2[tid] += red2[tid + off]; }
        __syncthreads();
    }
    if (tid == 0) {
        float mu = red[0] * (1.f / 16384.f);
        float var = red2[0] * (1.f / 16384.f) - mu * mu;
        mu_s = mu;
        rs_s = rsqrtf(var + 1e-5f);
    }
    __syncthreads();
    const float mu = mu_s, rs = rs_s;

#pragma unroll
    for (int i = 0; i < 16; i++) {
        float gm = gamma[g * 16 + i] * rs;
        float bt = beta[g * 16 + i] - mu * gm;
        float4 v = xr[i];
        f16x4 o;
        o[0] = (f16)(v.x * gm + bt);
        o[1] = (f16)(v.y * gm + bt);
        o[2] = (f16)(v.z * gm + bt);
        o[3] = (f16)(v.w * gm + bt);
        *(f16x4*)&T[i][tid * 4] = o;
    }
    __syncthreads();
#pragma unroll
    for (int i = 0; i < 8; i++) {
        int idx = tid + i * 256;
        int hw = idx >> 1;
        int half8 = (idx & 1) * 8;
        f16x8 o;
#pragma unroll
        for (int j = 0; j < 8; j++) o[j] = T[half8 + j][hw];
        long dst = ((long)b * 1024 + hw) * 512 + g * 16 + half8;
        *(f16x8*)(xnT + dst) = o;
    }
}

// ---------------- 128x128 MFMA GEMM (R4 core + XCD remap) ------------------------------------
// A stored [M][K] f16 (lda), B stored [N][K] f16 (ldb); async staged, double-buffered.
// MODE 0: scores: f16 out C[m][n] ld=N, *alpha (raw scaled scores). grid (8,8,16).
// MODE 1: QKV split: n0<1024 -> qkT[b][m][n]; n0>=1024 -> v[b][n-1024][m]; bias[n]. grid (12,8,16).
// MODE 2: proj: fp32 out + bias[m] + resid. grid (8,4,16).
// MODE 3: PV with fused softmax: A = raw S; prologue computes row max/sumexp; K-loop
//         exp-transforms A-frags; epilogue scales by 1/l; f16 out ld=N. grid (4,8,16).
template<int MODE>
__global__ __launch_bounds__(256)
void gemm_kernel(const f16* __restrict__ Ap, const f16* __restrict__ Bp,
                 void* __restrict__ Cp, f16* __restrict__ C2p,
                 const float* __restrict__ bias, const float* __restrict__ resid,
                 float alpha, int M, int N, int K, int lda, int ldb,
                 long sAb, long sBb, long sCb)
{
    __shared__ __align__(16) f16 As[2][128 * 32];
    __shared__ __align__(16) f16 Bs[2][128 * 32];
    __shared__ float sm[128][2], sl[128][2];   // MODE 3 stats scratch
    __shared__ float ec_s[128], il_s[128];     // MODE 3: m*log2e, 1/l per row

    // ---- XCD-aware remap from linear block id (8 XCDs, id%8 = XCD) ----
    const int linear = (blockIdx.z * gridDim.y + blockIdx.y) * gridDim.x + blockIdx.x;
    int mIdx, nIdx, bIdx;
    {
        const int x7 = linear & 7, slot = linear >> 3;
        if (MODE == 1) {            // 1536 blocks: A-tile (b,m) pinned to XCD; n sweeps
            nIdx = slot >> 4; int t = x7 + 8 * (slot & 15); mIdx = t & 7; bIdx = t >> 3;
        } else if (MODE == 0) {     // 1024 blocks: batch pinned to XCD (q,k resident)
            bIdx = x7 + 8 * (slot >> 6); int mn = slot & 63; mIdx = mn >> 3; nIdx = mn & 7;
        } else if (MODE == 3) {     // 512 blocks: batch pinned to XCD (S,v resident)
            bIdx = x7 + 8 * (slot >> 5); int mn = slot & 31; mIdx = mn >> 2; nIdx = mn & 3;
        } else {                    // MODE 2, 512 blocks: B-tile (b,n) pinned to XCD
            int t = x7 + 8 * (slot & 15); nIdx = t & 7; bIdx = t >> 3; mIdx = slot >> 4;
        }
    }
    const int b = bIdx;
    const int m0 = mIdx * 128, n0 = nIdx * 128;

    const int tid = threadIdx.x;
    const int wave = tid >> 6, lane = tid & 63;
    const int quad = lane >> 4, l15 = lane & 15;
    const int wm = (wave >> 1) * 64, wn = (wave & 1) * 64;
    const int chunkoff = (quad ^ (l15 & 3)) * 8;

    const f16* Ag = Ap + (long)b * sAb;
    const f16* Bg = Bp + (long)b * sBb;

    // ---- MODE 3 prologue: exact softmax stats for rows m0..m0+127 of S ----
    float cf[4];   // per-lane A-frag row consts (m*log2e), rows wm+tm*16+l15
    if (MODE == 3) {
        const int r_loc = tid >> 1, half = tid & 1;
        const f16* Srow = Ag + (long)(m0 + r_loc) * lda + half * 512;
        float mx = -3.0e38f;
        for (int ch = 0; ch < 64; ch += 8) {
#pragma unroll
            for (int u = 0; u < 8; u++) {
                f16x8 v8 = *(const f16x8*)(Srow + (ch + u) * 8);
#pragma unroll
                for (int j = 0; j < 8; j++) mx = fmaxf(mx, (float)v8[j]);
            }
        }
        float ssum = 0.f;
        const float nc = -mx * LOG2E;
        for (int ch = 0; ch < 64; ch += 8) {
#pragma unroll
            for (int u = 0; u < 8; u++) {
                f16x8 v8 = *(const f16x8*)(Srow + (ch + u) * 8);
#pragma unroll
                for (int j = 0; j < 8; j++) ssum += exp2f(fmaf((float)v8[j], LOG2E, nc));
            }
        }
        sm[r_loc][half] = mx;
        sl[r_loc][half] = ssum;
        __syncthreads();
        if (half == 0) {
            float m0h = sm[r_loc][0], m1h = sm[r_loc][1];
            float mrow = fmaxf(m0h, m1h);
            float l = sl[r_loc][0] * exp2f((m0h - mrow) * LOG2E)
                    + sl[r_loc][1] * exp2f((m1h - mrow) * LOG2E);
            ec_s[r_loc] = mrow * LOG2E;
            il_s[r_loc] = 1.f / l;
        }
        __syncthreads();
#pragma unroll
        for (int tm = 0; tm < 4; tm++) cf[tm] = ec_s[wm + tm * 16 + l15];
    }

    const int si = lane >> 2, sj = lane & 3;
    const int R0 = wave * 32, R1 = wave * 32 + 16;
    const f16* agA0 = Ag + (long)(m0 + R0 + si) * lda + ((sj ^ ((R0 + si) & 3)) * 8);
    const f16* agA1 = Ag + (long)(m0 + R1 + si) * lda + ((sj ^ ((R1 + si) & 3)) * 8);
    const f16* agB0 = Bg + (long)(n0 + R0 + si) * ldb + ((sj ^ ((R0 + si) & 3)) * 8);
    const f16* agB1 = Bg + (long)(n0 + R1 + si) * ldb + ((sj ^ ((R1 + si) & 3)) * 8);

    fx4 acc[4][4] = {};
    const int nIter = K >> 5;

#define STAGE(buf, kOff)                                          \
    { gload16(agA0 + (kOff), &As[buf][R0 * 32]);                   \
      gload16(agA1 + (kOff), &As[buf][R1 * 32]);                   \
      gload16(agB0 + (kOff), &Bs[buf][R0 * 32]);                   \
      gload16(agB1 + (kOff), &Bs[buf][R1 * 32]); }

    STAGE(0, 0)

    for (int it = 0; it < nIter; ++it) {
        __syncthreads();
        const int cur = it & 1;
        if (it + 1 < nIter) { STAGE(cur ^ 1, (it + 1) << 5) }
        f16x8 bf[4];
#pragma unroll
        for (int tn = 0; tn < 4; tn++)
            bf[tn] = *(const f16x8*)&Bs[cur][(wn + tn * 16 + l15) * 32 + chunkoff];
#pragma unroll
        for (int tm = 0; tm < 4; tm++) {
            f16x8 af = *(const f16x8*)&As[cur][(wm + tm * 16 + l15) * 32 + chunkoff];
            if (MODE == 3) {
                f16x8 pf;
#pragma unroll
                for (int j = 0; j < 8; j++)
                    pf[j] = (f16)exp2f(fmaf((float)af[j], LOG2E, -cf[tm]));
                af = pf;
            }
#pragma unroll
            for (int tn = 0; tn < 4; tn++)
                acc[tm][tn] = __builtin_amdgcn_mfma_f32_16x16x32_f16(af, bf[tn], acc[tm][tn], 0, 0, 0);
        }
    }
#undef STAGE

    // ---- epilogue: D[row = quad*4+r][col = l15] per 16x16 tile
    if (MODE == 1 && n0 >= 1024) {
#pragma unroll
        for (int tm = 0; tm < 4; tm++)
#pragma unroll
        for (int tn = 0; tn < 4; tn++) {
            int gc = n0 + wn + tn * 16 + l15;
            int gr0 = m0 + wm + tm * 16 + quad * 4;
            float bs = bias[gc];
            f16x4 o;
#pragma unroll
            for (int r = 0; r < 4; r++) o[r] = (f16)(acc[tm][tn][r] + bs);
            *(f16x4*)(C2p + (long)b * 524288 + (long)(gc - 1024) * 1024 + gr0) = o;
        }
        return;
    }
    float ilr[4][4];
    if (MODE == 3) {
#pragma unroll
        for (int tm = 0; tm < 4; tm++)
#pragma unroll
            for (int r = 0; r < 4; r++) ilr[tm][r] = il_s[wm + tm * 16 + quad * 4 + r];
    }
#pragma unroll
    for (int tm = 0; tm < 4; tm++)
#pragma unroll
    for (int tn = 0; tn < 4; tn++) {
        int gc = n0 + wn + tn * 16 + l15;
#pragma unroll
        for (int r = 0; r < 4; r++) {
            int gr = m0 + wm + tm * 16 + quad * 4 + r;
            float v = acc[tm][tn][r];
            if (MODE == 0) {
                v *= alpha;
                ((f16*)Cp)[(long)b * sCb + (long)gr * N + gc] = (f16)v;
            } else if (MODE == 3) {
                v *= ilr[tm][r];
                ((f16*)Cp)[(long)b * sCb + (long)gr * N + gc] = (f16)v;
            } else if (MODE == 1) {
                v += bias[gc];
                ((f16*)Cp)[(long)b * 1048576 + (long)gr * 1024 + gc] = (f16)v;
            } else {  // MODE 2
                v += bias[gr];
                long idx = (long)b * sCb + (long)gr * N + gc;
                v += resid[idx];
                ((float*)Cp)[idx] = v;
            }
        }
    }
}

extern "C" void kernel_launch(void* const* d_in, const int* in_sizes, int n_in,
                              void* d_out, int out_size, void* d_ws, size_t ws_size,
                              hipStream_t stream)
{
    const float* x      = (const float*)d_in[0];
    const float* gamma  = (const float*)d_in[1];
    const float* beta   = (const float*)d_in[2];
    const float* w_qkv  = (const float*)d_in[3];
    const float* b_qkv  = (const float*)d_in[4];
    const float* w_proj = (const float*)d_in[5];
    const float* b_proj = (const float*)d_in[6];
    float* out = (float*)d_out;

    char* ws = (char*)d_ws;
    f16* xnT   = (f16*)(ws);                 // 16 MB : [16][1024 hw][512 c]
    f16* qkT   = (f16*)(ws + (16L << 20));   // 32 MB : [16][1024 hw][1024 (q|k)]
    f16* vbuf  = (f16*)(ws + (48L << 20));   // 16 MB : [16][512 c][1024 hw]
    f16* S     = (f16*)(ws + (64L << 20));   // 32 MB : [16][1024 i][1024 j] raw scaled scores
    f16* aoutT = (f16*)(ws + (96L << 20));   // 16 MB : [16][1024 hw][512 c]
    f16* wqkvh = S;                          // 1.5 MB; overwritten by scores before PV reads S
    f16* wprjh = xnT;                        // 0.5 MB; written after QKV consumes xnT

    // 0) convert w_qkv fp32 -> f16
    wconv_kernel<<<768, 256, 0, stream>>>(w_qkv, wqkvh, 196608);

    // 1) GroupNorm -> xnT
    groupnorm_kernel<<<512, 256, 0, stream>>>(x, gamma, beta, xnT);

    // 2) QKV: C[m=hw][n=o] = xnT[hw][c] . w_qkv[o][c]; q,k -> qkT, v -> vbuf
    gemm_kernel<1><<<dim3(12, 8, 16), 256, 0, stream>>>(
        xnT, wqkvh, qkT, vbuf, b_qkv, nullptr, 1.0f,
        1024, 1536, 512, 512, 512,
        524288L, 0L, 0L);

    // 2b) convert w_proj fp32 -> f16 (xnT dead after QKV)
    wconv_kernel<<<256, 256, 0, stream>>>(w_proj, wprjh, 65536);

    // 3) Scores (raw, alpha-scaled): S[i][j] = scale * q[i][c] . k[j][c]
    gemm_kernel<0><<<dim3(8, 8, 16), 256, 0, stream>>>(
        qkT, qkT + 512, S, nullptr, nullptr, nullptr, 0.04419417382415922f,
        1024, 1024, 512, 1024, 1024,
        1048576L, 1048576L, 1048576L);

    // 4) PV + fused softmax: aoutT[i][c] = (sum_j exp(S[i][j]-m_i) v[c][j]) / l_i
    gemm_kernel<3><<<dim3(4, 8, 16), 256, 0, stream>>>(
        S, vbuf, aoutT, nullptr, nullptr, nullptr, 1.0f,
        1024, 512, 1024, 1024, 1024,
        1048576L, 524288L, 524288L);

    // 5) Proj: out[o][hw] = w_proj[o][c] . aoutT[hw][c] + b_proj[o] + x
    gemm_kernel<2><<<dim3(8, 4, 16), 256, 0, stream>>>(
        wprjh, aoutT, out, nullptr, b_proj, x, 1.0f,
        512, 1024, 512, 512, 512,
        0L, 524288L, 524288L);
}

// Round 8
// 239.189 us; speedup vs baseline: 1.1618x; 1.1618x over previous
//
#include <hip/hip_runtime.h>

// SelfAttention: GN -> 1x1 QKV -> softmax attention (HW=1024) -> 1x1 proj + residual
// B=16, C=512, HW=1024, GROUPS=32, EPS=1e-5, scale=C^-0.5
//
// Round 8: occupancy fix. All prior rounds: OccupancyPercent ~17% (=~1.4 blocks/CU)
// because grids were 2-6 blocks/CU total. Smaller tiles: BM=64 x BN=128, 4 waves of
// 32x64 (acc[2][4]), LDS 24 KB dbuf -> grids 1024-3072 blocks (4-12/CU). PV reverted
// to plain GEMM + separate softmax (R7 fusion cost 50us VALU for 25us saved BW).
// Generic XCD remap: batch pinned to XCD (one batch resident per XCD at a time,
// working set fits 4MB L2). Core = R4 barriered double-buffer, global_load_lds w16,
// XOR chunk swizzle. Layouts (all [free][K]):
//   xnT [b][hw][c], qkT [b][hw][q|k], v [b][c][hw], S/P [b][i][j], aoutT [b][hw][c]

typedef _Float16 f16;
typedef _Float16 f16x8 __attribute__((ext_vector_type(8)));
typedef _Float16 f16x4 __attribute__((ext_vector_type(4)));
typedef float fx4 __attribute__((ext_vector_type(4)));

__device__ __forceinline__ void gload16(const f16* g, f16* l) {
    __builtin_amdgcn_global_load_lds((const __attribute__((address_space(1))) void*)g,
                                     (__attribute__((address_space(3))) void*)l, 16, 0, 0);
}

// ---------------- weight convert: fp32 -> f16, n4 float4 chunks ----------------
__global__ __launch_bounds__(256)
void wconv_kernel(const float* __restrict__ w, f16* __restrict__ o, int n4)
{
    int i = blockIdx.x * 256 + threadIdx.x;
    if (i < n4) {
        float4 v = *(const float4*)(w + i * 4);
        f16x4 h;
        h[0] = (f16)v.x; h[1] = (f16)v.y; h[2] = (f16)v.z; h[3] = (f16)v.w;
        *(f16x4*)(o + i * 4) = h;
    }
}

// ---------------- GroupNorm: x fp32 [16][512][1024] -> xnT f16 [16][1024][512] ----------------
__global__ __launch_bounds__(256)
void groupnorm_kernel(const float* __restrict__ x, const float* __restrict__ gamma,
                      const float* __restrict__ beta, f16* __restrict__ xnT)
{
    __shared__ float red[256], red2[256];
    __shared__ float mu_s, rs_s;
    __shared__ __align__(16) f16 T[16][1040];  // [ch][hw], padded
    const int blk = blockIdx.x;                // b*32 + g
    const int b = blk >> 5, g = blk & 31;
    const long base = (long)blk * 16384;       // 16 ch * 1024 hw
    const int tid = threadIdx.x;
    const float4* xv = (const float4*)(x + base);

    float4 xr[16];
    float s = 0.f, s2 = 0.f;
#pragma unroll
    for (int i = 0; i < 16; i++) {
        float4 v = xv[tid + i * 256];
        xr[i] = v;
        s  += v.x + v.y + v.z + v.w;
        s2 += v.x * v.x + v.y * v.y + v.z * v.z + v.w * v.w;
    }
    red[tid] = s; red2[tid] = s2;
    __syncthreads();
    for (int off = 128; off > 0; off >>= 1) {
        if (tid < off) { red[tid] += red[tid + off]; red2[tid] += red2[tid + off]; }
        __syncthreads();
    }
    if (tid == 0) {
        float mu = red[0] * (1.f / 16384.f);
        float var = red2[0] * (1.f / 16384.f) - mu * mu;
        mu_s = mu;
        rs_s = rsqrtf(var + 1e-5f);
    }
    __syncthreads();
    const float mu = mu_s, rs = rs_s;

#pragma unroll
    for (int i = 0; i < 16; i++) {
        float gm = gamma[g * 16 + i] * rs;
        float bt = beta[g * 16 + i] - mu * gm;
        float4 v = xr[i];
        f16x4 o;
        o[0] = (f16)(v.x * gm + bt);
        o[1] = (f16)(v.y * gm + bt);
        o[2] = (f16)(v.z * gm + bt);
        o[3] = (f16)(v.w * gm + bt);
        *(f16x4*)&T[i][tid * 4] = o;
    }
    __syncthreads();
#pragma unroll
    for (int i = 0; i < 8; i++) {
        int idx = tid + i * 256;
        int hw = idx >> 1;
        int half8 = (idx & 1) * 8;
        f16x8 o;
#pragma unroll
        for (int j = 0; j < 8; j++) o[j] = T[half8 + j][hw];
        long dst = ((long)b * 1024 + hw) * 512 + g * 16 + half8;
        *(f16x8*)(xnT + dst) = o;
    }
}

// ---------------- Row softmax over j: S f16 [16][1024][1024], one wave per row ----------------
__global__ __launch_bounds__(256)
void softmax_kernel(f16* __restrict__ S)
{
    const int wid = blockIdx.x * 4 + (threadIdx.x >> 6);
    const int lane = threadIdx.x & 63;
    f16* p = S + (long)wid * 1024 + lane * 16;
    f16x8 h0 = *(const f16x8*)p;
    f16x8 h1 = *(const f16x8*)(p + 8);
    float v[16];
#pragma unroll
    for (int i = 0; i < 8; i++) { v[i] = (float)h0[i]; v[8 + i] = (float)h1[i]; }
    float mx = v[0];
#pragma unroll
    for (int i = 1; i < 16; i++) mx = fmaxf(mx, v[i]);
    for (int off = 32; off > 0; off >>= 1) mx = fmaxf(mx, __shfl_xor(mx, off, 64));
    float sum = 0.f;
#pragma unroll
    for (int i = 0; i < 16; i++) { v[i] = __expf(v[i] - mx); sum += v[i]; }
    for (int off = 32; off > 0; off >>= 1) sum += __shfl_xor(sum, off, 64);
    const float inv = 1.f / sum;
#pragma unroll
    for (int i = 0; i < 8; i++) { h0[i] = (f16)(v[i] * inv); h1[i] = (f16)(v[8 + i] * inv); }
    *(f16x8*)p = h0;
    *(f16x8*)(p + 8) = h1;
}

// ---------------- 64x128 MFMA GEMM, 4 waves of 32x64, barriered double-buffer -----------------
// A stored [M][K] f16 (lda), B stored [N][K] f16 (ldb); async staged via global_load_lds w16.
// Generic XCD remap: one batch pinned per XCD at a time; within batch, n sweeps fastest
// (A-tile reuse). MODE 0: f16 out C[m][n] ld=N, *alpha. MODE 1: QKV split (q,k -> qkT;
// v transposed -> C2p; bias[n]). MODE 2: fp32 out + bias[m] + resid.
template<int MODE>
__global__ __launch_bounds__(256)
void gemm_kernel(const f16* __restrict__ Ap, const f16* __restrict__ Bp,
                 void* __restrict__ Cp, f16* __restrict__ C2p,
                 const float* __restrict__ bias, const float* __restrict__ resid,
                 float alpha, int M, int N, int K, int lda, int ldb,
                 long sAb, long sBb, long sCb)
{
    __shared__ __align__(16) f16 As[2][64 * 32];    //  8 KB
    __shared__ __align__(16) f16 Bs[2][128 * 32];   // 16 KB

    // ---- XCD remap: linear -> (b, mIdx, nIdx); 8 XCDs, linear&7 = XCD ----
    const int linear = (blockIdx.z * gridDim.y + blockIdx.y) * gridDim.x + blockIdx.x;
    const int nTiles = gridDim.x, nm = gridDim.x * gridDim.y;   // blocks per batch
    const int x7 = linear & 7, slot = linear >> 3;
    const int b = x7 + 8 * (slot / nm);
    const int rem = slot % nm;
    const int mIdx = rem / nTiles, nIdx = rem % nTiles;
    const int m0 = mIdx * 64, n0 = nIdx * 128;

    const int tid = threadIdx.x;
    const int wave = tid >> 6, lane = tid & 63;
    const int quad = lane >> 4, l15 = lane & 15;
    const int wm = (wave >> 1) * 32, wn = (wave & 1) * 64;
    const int chunkoff = (quad ^ (l15 & 3)) * 8;    // loop-invariant frag chunk (XOR swizzle)

    const f16* Ag = Ap + (long)b * sAb;
    const f16* Bg = Bp + (long)b * sBb;

    const int si = lane >> 2, sj = lane & 3;
    // A: 1 staging instr/wave (16 rows at R=wave*16); B: 2 instrs/wave (rows wave*32, +16)
    const int RA = wave * 16, RB0 = wave * 32, RB1 = wave * 32 + 16;
    const f16* agA  = Ag + (long)(m0 + RA  + si) * lda + ((sj ^ ((RA  + si) & 3)) * 8);
    const f16* agB0 = Bg + (long)(n0 + RB0 + si) * ldb + ((sj ^ ((RB0 + si) & 3)) * 8);
    const f16* agB1 = Bg + (long)(n0 + RB1 + si) * ldb + ((sj ^ ((RB1 + si) & 3)) * 8);

    fx4 acc[2][4] = {};
    const int nIter = K >> 5;

#define STAGE(buf, kOff)                                          \
    { gload16(agA  + (kOff), &As[buf][RA  * 32]);                  \
      gload16(agB0 + (kOff), &Bs[buf][RB0 * 32]);                  \
      gload16(agB1 + (kOff), &Bs[buf][RB1 * 32]); }

    STAGE(0, 0)

    for (int it = 0; it < nIter; ++it) {
        __syncthreads();
        const int cur = it & 1;
        if (it + 1 < nIter) { STAGE(cur ^ 1, (it + 1) << 5) }
        f16x8 bf[4];
#pragma unroll
        for (int tn = 0; tn < 4; tn++)
            bf[tn] = *(const f16x8*)&Bs[cur][(wn + tn * 16 + l15) * 32 + chunkoff];
#pragma unroll
        for (int tm = 0; tm < 2; tm++) {
            f16x8 af = *(const f16x8*)&As[cur][(wm + tm * 16 + l15) * 32 + chunkoff];
#pragma unroll
            for (int tn = 0; tn < 4; tn++)
                acc[tm][tn] = __builtin_amdgcn_mfma_f32_16x16x32_f16(af, bf[tn], acc[tm][tn], 0, 0, 0);
        }
    }
#undef STAGE

    // ---- epilogue: D[row = quad*4+r][col = l15] per 16x16 tile
    if (MODE == 1 && n0 >= 1024) {
        // v-part: write transposed to v[b][c][hw], vectorized f16x4 along hw(=m)
#pragma unroll
        for (int tm = 0; tm < 2; tm++)
#pragma unroll
        for (int tn = 0; tn < 4; tn++) {
            int gc = n0 + wn + tn * 16 + l15;
            int gr0 = m0 + wm + tm * 16 + quad * 4;
            float bs = bias[gc];
            f16x4 o;
#pragma unroll
            for (int r = 0; r < 4; r++) o[r] = (f16)(acc[tm][tn][r] + bs);
            *(f16x4*)(C2p + (long)b * 524288 + (long)(gc - 1024) * 1024 + gr0) = o;
        }
        return;
    }
#pragma unroll
    for (int tm = 0; tm < 2; tm++)
#pragma unroll
    for (int tn = 0; tn < 4; tn++) {
        int gc = n0 + wn + tn * 16 + l15;
#pragma unroll
        for (int r = 0; r < 4; r++) {
            int gr = m0 + wm + tm * 16 + quad * 4 + r;
            float v = acc[tm][tn][r];
            if (MODE == 0) {
                v *= alpha;
                ((f16*)Cp)[(long)b * sCb + (long)gr * N + gc] = (f16)v;
            } else if (MODE == 1) {
                v += bias[gc];
                ((f16*)Cp)[(long)b * 1048576 + (long)gr * 1024 + gc] = (f16)v;
            } else {  // MODE 2
                v += bias[gr];
                long idx = (long)b * sCb + (long)gr * N + gc;
                v += resid[idx];
                ((float*)Cp)[idx] = v;
            }
        }
    }
}

extern "C" void kernel_launch(void* const* d_in, const int* in_sizes, int n_in,
                              void* d_out, int out_size, void* d_ws, size_t ws_size,
                              hipStream_t stream)
{
    const float* x      = (const float*)d_in[0];
    const float* gamma  = (const float*)d_in[1];
    const float* beta   = (const float*)d_in[2];
    const float* w_qkv  = (const float*)d_in[3];
    const float* b_qkv  = (const float*)d_in[4];
    const float* w_proj = (const float*)d_in[5];
    const float* b_proj = (const float*)d_in[6];
    float* out = (float*)d_out;

    char* ws = (char*)d_ws;
    f16* xnT   = (f16*)(ws);                 // 16 MB : [16][1024 hw][512 c]
    f16* qkT   = (f16*)(ws + (16L << 20));   // 32 MB : [16][1024 hw][1024 (q|k)]
    f16* vbuf  = (f16*)(ws + (48L << 20));   // 16 MB : [16][512 c][1024 hw]
    f16* S     = (f16*)(ws + (64L << 20));   // 32 MB : [16][1024 i][1024 j]
    f16* aoutT = (f16*)(ws + (96L << 20));   // 16 MB : [16][1024 hw][512 c]
    f16* wqkvh = S;                          // 1.5 MB; dead before scores writes S
    f16* wprjh = xnT;                        // 0.5 MB; written after QKV consumes xnT

    // 0) convert w_qkv fp32 -> f16
    wconv_kernel<<<768, 256, 0, stream>>>(w_qkv, wqkvh, 196608);

    // 1) GroupNorm -> xnT
    groupnorm_kernel<<<512, 256, 0, stream>>>(x, gamma, beta, xnT);

    // 2) QKV: C[m=hw][n=o] = xnT[hw][c] . w_qkv[o][c]; q,k -> qkT, v -> vbuf
    gemm_kernel<1><<<dim3(12, 16, 16), 256, 0, stream>>>(
        xnT, wqkvh, qkT, vbuf, b_qkv, nullptr, 1.0f,
        1024, 1536, 512, 512, 512,
        524288L, 0L, 0L);

    // 2b) convert w_proj fp32 -> f16 (xnT dead after QKV)
    wconv_kernel<<<256, 256, 0, stream>>>(w_proj, wprjh, 65536);

    // 3) Scores: S[i][j] = scale * q[i][c] . k[j][c]
    gemm_kernel<0><<<dim3(8, 16, 16), 256, 0, stream>>>(
        qkT, qkT + 512, S, nullptr, nullptr, nullptr, 0.04419417382415922f,
        1024, 1024, 512, 1024, 1024,
        1048576L, 1048576L, 1048576L);

    // 4) Softmax over j
    softmax_kernel<<<4096, 256, 0, stream>>>(S);

    // 5) PV: aoutT[i][c] = P[i][j] . v[c][j]
    gemm_kernel<0><<<dim3(4, 16, 16), 256, 0, stream>>>(
        S, vbuf, aoutT, nullptr, nullptr, nullptr, 1.0f,
        1024, 512, 1024, 1024, 1024,
        1048576L, 524288L, 524288L);

    // 6) Proj: out[o][hw] = w_proj[o][c] . aoutT[hw][c] + b_proj[o] + x
    gemm_kernel<2><<<dim3(8, 8, 16), 256, 0, stream>>>(
        wprjh, aoutT, out, nullptr, b_proj, x, 1.0f,
        512, 1024, 512, 512, 512,
        0L, 524288L, 524288L);
}